// Round 1
// baseline (767.623 us; speedup 1.0000x reference)
//
#include <hip/hip_runtime.h>
#include <hip/hip_bf16.h>
#include <math.h>

typedef unsigned short u16;
typedef __attribute__((ext_vector_type(8))) short short8;
typedef __attribute__((ext_vector_type(4))) float f32x4;

#define T_STEPS 10
#define NB 8
#define HH 64
#define WW 64
#define FF 64
#define NGATE 256
#define HP 66
#define PIX (NB*HH*WW)          // 32768
#define GEMM_BLOCKS (PIX/64)    // 512

__device__ __forceinline__ u16 f2bf(float f) {
    unsigned u = __float_as_uint(f);
    u += 0x7FFF + ((u >> 16) & 1);   // round-to-nearest-even
    return (u16)(u >> 16);
}
__device__ __forceinline__ float hsig(float x) {
    return fminf(fmaxf(0.2f * x + 0.5f, 0.0f), 1.0f);
}

// Transpose fp32 [K][256] weight(s) -> bf16 BT [256][K]. For K=1152 the first
// 576 rows come from W0 (input kernel) and the rest from W1 (recurrent kernel).
__global__ void wtrans_kernel(const float* __restrict__ W0,
                              const float* __restrict__ W1,
                              u16* __restrict__ BT, int K) {
    int total = K * NGATE;
    for (int o = blockIdx.x * blockDim.x + threadIdx.x; o < total;
         o += gridDim.x * blockDim.x) {
        int n = o / K, k = o - n * K;
        float v = (k < 576) ? W0[k * NGATE + n] : W1[(k - 576) * NGATE + n];
        BT[o] = f2bf(v);
    }
}

// Layer-0 input conv (Cin=1) + bias -> zbuf[p][256], fp32 exact.
__global__ void zinit_kernel(const float* __restrict__ x,
                             const float* __restrict__ k0,
                             const float* __restrict__ b0,
                             float* __restrict__ zbuf, int t) {
    __shared__ float xs[3][WW + 2];
    int blk = blockIdx.x;            // one image row per block
    int b = blk >> 6, y = blk & 63;
    int tid = threadIdx.x;           // 256 threads
    if (tid < 3 * (WW + 2)) {
        int dyi = tid / (WW + 2), xx = tid - dyi * (WW + 2);
        int yy = y + dyi - 1, xcol = xx - 1;
        float v = 0.0f;
        if (yy >= 0 && yy < HH && xcol >= 0 && xcol < WW)
            v = x[(((size_t)b * T_STEPS + t) * HH + yy) * WW + xcol];
        xs[dyi][xx] = v;
    }
    __syncthreads();
    int n = tid;                     // output channel
    float w[9];
#pragma unroll
    for (int tau = 0; tau < 9; ++tau) w[tau] = k0[tau * NGATE + n];
    float bias = b0[n];
    float* zrow = zbuf + (size_t)blk * 64 * NGATE + n;
    for (int px = 0; px < WW; ++px) {
        float acc = bias;
#pragma unroll
        for (int tau = 0; tau < 9; ++tau)
            acc += xs[tau / 3][px + (tau % 3)] * w[tau];
        zrow[(size_t)px * NGATE] = acc;
    }
}

// Implicit-GEMM conv (3x3 SAME) + fused ConvLSTM gate update.
// A: 64 pixels (one image row) x K from padded bf16 h buffers.
// B: BT [256][K] bf16 (pre-transposed weights).
// Epilogue: z -> gates -> c,h update. h written bf16 into padded hpad_out.
__global__ __launch_bounds__(256)
void gemm_lstm_kernel(const u16* __restrict__ Ah0,  // taps 0..8 source (padded)
                      const u16* __restrict__ Ah1,  // taps 9..17 source or null
                      const u16* __restrict__ BT,   // [256][K]
                      int K,
                      const float* __restrict__ zinit,  // [PIX][256] or null
                      const float* __restrict__ bias,   // [256] or null
                      float* __restrict__ cbuf,         // [PIX][64]
                      u16* __restrict__ hpad_out,       // padded (8,66,66,64)
                      float* __restrict__ outh,
                      float* __restrict__ outc,
                      int write_out) {
    __shared__ __align__(16) u16 sA[64][72];
    __shared__ __align__(16) u16 sB[256][72];

    int tid = threadIdx.x;
    int wave = tid >> 6, lane = tid & 63;
    int blk = blockIdx.x;
    int b = blk >> 6, y = blk & 63;

    f32x4 acc[4][4];
#pragma unroll
    for (int mt = 0; mt < 4; ++mt)
#pragma unroll
        for (int g = 0; g < 4; ++g)
            acc[mt][g] = (f32x4){0.f, 0.f, 0.f, 0.f};

    int nchunks = K >> 6;
    int a_px = tid >> 2, a_q = tid & 3;      // A staging: pixel, 16-ch quarter
    int b_row0 = tid >> 3, b_part = tid & 7; // B staging: row base, 8-k part

    for (int kc = 0; kc < nchunks; ++kc) {
        int tau = (kc < 9) ? kc : kc - 9;
        const u16* src = (kc < 9) ? Ah0 : Ah1;
        int dy = tau / 3 - 1, dx = tau % 3 - 1;
        {   // A tile: 64 px x 64 ch for this tap (halo makes it branch-free)
            int yy = y + dy + 1;
            int xx = a_px + dx + 1;
            const u16* gp = src + (((size_t)(b * HP + yy)) * HP + xx) * FF + a_q * 16;
            *(uint4*)&sA[a_px][a_q * 16]     = *(const uint4*)gp;
            *(uint4*)&sA[a_px][a_q * 16 + 8] = *(const uint4*)(gp + 8);
        }
        {   // B tile: 256 n x 64 k
            const u16* gb = BT + (size_t)kc * 64 + b_part * 8;
#pragma unroll
            for (int pass = 0; pass < 8; ++pass) {
                int n = pass * 32 + b_row0;
                *(uint4*)&sB[n][b_part * 8] = *(const uint4*)(gb + (size_t)n * K);
            }
        }
        __syncthreads();
#pragma unroll
        for (int ks = 0; ks < 2; ++ks) {
            short8 aF[4], bF[4];
            int ko = ks * 32 + (lane >> 4) * 8;
#pragma unroll
            for (int mt = 0; mt < 4; ++mt)
                aF[mt] = *(const short8*)&sA[mt * 16 + (lane & 15)][ko];
#pragma unroll
            for (int g = 0; g < 4; ++g)
                bF[g] = *(const short8*)&sB[g * 64 + wave * 16 + (lane & 15)][ko];
#pragma unroll
            for (int mt = 0; mt < 4; ++mt)
#pragma unroll
                for (int g = 0; g < 4; ++g)
                    acc[mt][g] = __builtin_amdgcn_mfma_f32_16x16x32_bf16(
                        aF[mt], bF[g], acc[mt][g], 0, 0, 0);
        }
        __syncthreads();
    }

    // Epilogue: gate update. Wave w owns f-cols 16w..16w+15 across all 4 gates.
    int f = wave * 16 + (lane & 15);
    int quad = lane >> 4;
    float bi = 0.f, bff = 0.f, bg = 0.f, bo = 0.f;
    if (bias) { bi = bias[f]; bff = bias[64 + f]; bg = bias[128 + f]; bo = bias[192 + f]; }
#pragma unroll
    for (int mt = 0; mt < 4; ++mt) {
#pragma unroll
        for (int r = 0; r < 4; ++r) {
            int row = mt * 16 + quad * 4 + r;   // x coordinate within the row
            size_t p = (size_t)blk * 64 + row;  // global pixel
            float zi = acc[mt][0][r], zf = acc[mt][1][r];
            float zg = acc[mt][2][r], zo = acc[mt][3][r];
            if (zinit) {
                const float* zp = zinit + p * NGATE;
                zi += zp[f]; zf += zp[64 + f]; zg += zp[128 + f]; zo += zp[192 + f];
            } else {
                zi += bi; zf += bff; zg += bg; zo += bo;
            }
            float cold = cbuf[p * FF + f];
            float cn = hsig(zf) * cold + hsig(zi) * tanhf(zg);
            float hn = hsig(zo) * tanhf(cn);
            cbuf[p * FF + f] = cn;
            hpad_out[(((size_t)(b * HP + y + 1)) * HP + (row + 1)) * FF + f] = f2bf(hn);
            if (write_out) { outh[p * FF + f] = hn; outc[p * FF + f] = cn; }
        }
    }
}

extern "C" void kernel_launch(void* const* d_in, const int* in_sizes, int n_in,
                              void* d_out, int out_size, void* d_ws, size_t ws_size,
                              hipStream_t stream) {
    const float* x   = (const float*)d_in[0];
    const float* k0  = (const float*)d_in[1];
    const float* rk0 = (const float*)d_in[2];
    const float* b0  = (const float*)d_in[3];
    const float* k1  = (const float*)d_in[4];
    const float* rk1 = (const float*)d_in[5];
    const float* b1  = (const float*)d_in[6];
    float* out = (float*)d_out;

    char* ws = (char*)d_ws;
    const size_t HPAD_BYTES = (size_t)NB * HP * HP * FF * 2;  // 4,460,544
    const size_t C_BYTES    = (size_t)PIX * FF * 4;           // 8,388,608
    const size_t Z_BYTES    = (size_t)PIX * NGATE * 4;        // 33,554,432

    u16* h0p[2]; u16* h1p[2];
    h0p[0] = (u16*)(ws);
    h0p[1] = (u16*)(ws + HPAD_BYTES);
    h1p[0] = (u16*)(ws + 2 * HPAD_BYTES);
    h1p[1] = (u16*)(ws + 3 * HPAD_BYTES);
    float* c0   = (float*)(ws + 4 * HPAD_BYTES);
    float* c1   = (float*)(ws + 4 * HPAD_BYTES + C_BYTES);
    float* zbuf = (float*)(ws + 4 * HPAD_BYTES + 2 * C_BYTES);
    u16* B0T    = (u16*)(ws + 4 * HPAD_BYTES + 2 * C_BYTES + Z_BYTES);
    u16* B1T    = (u16*)(ws + 4 * HPAD_BYTES + 2 * C_BYTES + Z_BYTES + (size_t)576 * 256 * 2);

    // Zero h (incl. halo == SAME padding) and c states; ws is poisoned 0xAA.
    hipMemsetAsync(ws, 0, 4 * HPAD_BYTES + 2 * C_BYTES, stream);

    // Weights -> bf16, transposed to [N][K] once per launch.
    wtrans_kernel<<<256, 256, 0, stream>>>(rk0, rk0, B0T, 576);
    wtrans_kernel<<<256, 256, 0, stream>>>(k1, rk1, B1T, 1152);

    float* oh0 = out;
    float* oc0 = out + (size_t)PIX * FF;
    float* oh1 = out + 2 * (size_t)PIX * FF;
    float* oc1 = out + 3 * (size_t)PIX * FF;

    for (int t = 0; t < T_STEPS; ++t) {
        int par = t & 1;
        int wo = (t == T_STEPS - 1) ? 1 : 0;
        zinit_kernel<<<GEMM_BLOCKS, 256, 0, stream>>>(x, k0, b0, zbuf, t);
        // Layer 0: z = zbuf + conv(h0_prev, rk0); writes h0 (new), c0.
        gemm_lstm_kernel<<<GEMM_BLOCKS, 256, 0, stream>>>(
            h0p[par], nullptr, B0T, 576, zbuf, nullptr,
            c0, h0p[par ^ 1], oh0, oc0, wo);
        // Layer 1: z = conv(h0_new, k1) + conv(h1_prev, rk1) + b1.
        gemm_lstm_kernel<<<GEMM_BLOCKS, 256, 0, stream>>>(
            h0p[par ^ 1], h1p[par], B1T, 1152, nullptr, b1,
            c1, h1p[par ^ 1], oh1, oc1, wo);
    }
}